// Round 7
// baseline (307.901 us; speedup 1.0000x reference)
//
#include <hip/hip_runtime.h>

// adaptive_aggregationPC: out[b,0,h,w] = sum_{dh,dw} sal[b, h+dh-2, w+dw-2] * agg[b, dh*5+dw, h, w]
// sal = max(thick, thin), zero padding. B=8, H=W=512, fp32.
// R4 post-mortem: kernel ~103us vs 36us BW floor; VALU-issue-bound
// (480 VALU/thread * 262K threads / 1024 SIMDs * 2cy = ~102us. Matches.)
// R5: (1) sal precomputed into zero-PADDED plane in d_ws -> no fmax*5, no halo
// selects, no row branch in main kernel; (2) readfirstlane-scalarized addressing
// (b,h wave-uniform: 1 wave == 1 row) -> s_base + v_off loads.

constexpr int K = 5;
constexpr int HH = 512, WW = 512;
constexpr int SW = WW + 16;      // padded stride: 8 left, 8 right
constexpr int SH = HH + 4;       // 2 top, 2 bottom
constexpr int SPLANE = SH * SW;  // 516*528 floats
constexpr int PLANE = HH * WW;

typedef float vf4 __attribute__((ext_vector_type(4)));

// kernel 1: sal_padded[b][hp][wp] = (interior) ? max(thick,thin)[b][hp-2][wp-8] : 0
__global__ __launch_bounds__(256) void sal_pad_kernel(
    const float* __restrict__ thick,
    const float* __restrict__ thin,
    float* __restrict__ sal, int B)
{
    const int nw = SW / 4;  // 132 float4-groups per padded row
    int tid = blockIdx.x * blockDim.x + threadIdx.x;
    int wp = (tid % nw) * 4;
    int hp = (tid / nw) % SH;
    int b  = tid / (nw * SH);
    if (b >= B) return;

    vf4 v = {0.f, 0.f, 0.f, 0.f};
    int h = hp - 2, w = wp - 8;   // wp%4==0 and 8,520 are multiples of 4 -> group all-in or all-out
    if (h >= 0 && h < HH && w >= 0 && w < WW) {
        const float* tk = thick + ((size_t)b * HH + h) * WW + w;
        const float* tn = thin  + ((size_t)b * HH + h) * WW + w;
        vf4 a = *(const vf4*)tk;
        vf4 c = *(const vf4*)tn;
        v.x = fmaxf(a.x, c.x); v.y = fmaxf(a.y, c.y);
        v.z = fmaxf(a.z, c.z); v.w = fmaxf(a.w, c.w);
    }
    *(vf4*)(sal + (size_t)b * SPLANE + (size_t)hp * SW + wp) = v;
}

// kernel 2: pure load+FMA aggregation. 8 px/thread, 1 wave == 1 output row.
__global__ __launch_bounds__(256) void agg_kernel(
    const float* __restrict__ sal,
    const float* __restrict__ agg,
    float* __restrict__ out, int B)
{
    const int wq = WW >> 3;  // 64 -> one wave per row
    int tid = blockIdx.x * blockDim.x + threadIdx.x;
    int w0 = (tid % wq) << 3;
    int h  = (tid / wq) % HH;
    int b  = tid / (wq * HH);
    if (b >= B) return;

    // wave-uniform offsets forced to SGPR (b,h constant across the wave)
    int sal_base = __builtin_amdgcn_readfirstlane(b * SPLANE + h * SW + 8);
    int agg_base = __builtin_amdgcn_readfirstlane(b * (K * K) * PLANE + h * WW);
    int out_base = __builtin_amdgcn_readfirstlane(b * PLANE + h * WW);

    float acc[8];
    #pragma unroll
    for (int p = 0; p < 8; ++p) acc[p] = 0.f;

    #pragma unroll
    for (int dh = 0; dh < K; ++dh) {
        // padded row hp = h + dh; left pad folded into sal_base (+8)
        const float* srp = sal + sal_base + dh * SW + (w0 - 4);
        vf4 s0 = *(const vf4*)(srp);
        vf4 s1 = *(const vf4*)(srp + 4);
        vf4 s2 = *(const vf4*)(srp + 8);
        vf4 s3 = *(const vf4*)(srp + 12);
        float srow[16];
        #pragma unroll
        for (int e = 0; e < 4; ++e) {
            srow[e] = s0[e]; srow[4 + e] = s1[e];
            srow[8 + e] = s2[e]; srow[12 + e] = s3[e];
        }
        // borders are real zeros in the padded plane: no selects, no branches
        #pragma unroll
        for (int dw = 0; dw < K; ++dw) {
            const float* ap = agg + agg_base + (dh * K + dw) * PLANE + w0;
            vf4 c0 = __builtin_nontemporal_load((const vf4*)ap);
            vf4 c1 = __builtin_nontemporal_load((const vf4*)(ap + 4));
            #pragma unroll
            for (int e = 0; e < 4; ++e) {
                acc[e]     = fmaf(c0[e], srow[2 + dw + e],     acc[e]);
                acc[4 + e] = fmaf(c1[e], srow[2 + dw + 4 + e], acc[4 + e]);
            }
        }
    }

    float* op = out + out_base + w0;
    vf4 o0 = {acc[0], acc[1], acc[2], acc[3]};
    vf4 o1 = {acc[4], acc[5], acc[6], acc[7]};
    __builtin_nontemporal_store(o0, (vf4*)op);
    __builtin_nontemporal_store(o1, (vf4*)(op + 4));
}

extern "C" void kernel_launch(void* const* d_in, const int* in_sizes, int n_in,
                              void* d_out, int out_size, void* d_ws, size_t ws_size,
                              hipStream_t stream) {
    const float* thick = (const float*)d_in[0];
    const float* thin  = (const float*)d_in[1];
    const float* agg   = (const float*)d_in[2];
    float* out = (float*)d_out;
    float* sal = (float*)d_ws;   // B*SPLANE floats = 8.7 MB << ws_size

    const int B = in_sizes[0] / PLANE;   // = 8

    int t1 = B * SH * (SW / 4);
    sal_pad_kernel<<<(t1 + 255) / 256, 256, 0, stream>>>(thick, thin, sal, B);

    int t2 = B * HH * (WW / 8);
    agg_kernel<<<(t2 + 255) / 256, 256, 0, stream>>>(sal, agg, out, B);
}